// Round 6
// baseline (238.293 us; speedup 1.0000x reference)
//
#include <hip/hip_runtime.h>
#include <hip/hip_bf16.h>

// COO SpMM: out[row[e], :] += ev[e] * x[col[e], :]
// N=100000, E=1600000, D=128 fp32.
//
// Round 6: round-5 plan with compile fix (__builtin_nontemporal_store needs
// scalar/vector-of-scalar pointers -> store packed pairs via long long alias).
// bf16 gather copy of x halves the fetch-bound gather's bytes; convert fused
// into hist pass; scan3 folded into scatter/gather.

#define D_FEAT 128

typedef float f32x2 __attribute__((ext_vector_type(2)));

static __device__ __forceinline__ unsigned short f2bf(float f) {
    unsigned u = __float_as_uint(f);
    u += 0x7fffu + ((u >> 16) & 1u);   // round-to-nearest-even
    return (unsigned short)(u >> 16);
}

// ---------------- fused convert(x->bf16) + histogram(+rank) ----------------

__global__ __launch_bounds__(256) void convert_hist_kernel(
    const float* __restrict__ x, unsigned long long* __restrict__ xh64, int nfeat4,
    const int* __restrict__ rows, int* __restrict__ counts,
    int* __restrict__ rank, int E) {
    int gid = blockIdx.x * 256 + threadIdx.x;
    int gsz = gridDim.x * 256;

    // x fp32 -> bf16 (stream, independent of hist). 4 floats -> 1 u64.
    const float4* x4 = reinterpret_cast<const float4*>(x);
    for (int i = gid; i < nfeat4; i += gsz) {
        float4 v = x4[i];
        unsigned long long h =
            (unsigned long long)f2bf(v.x)
          | ((unsigned long long)f2bf(v.y) << 16)
          | ((unsigned long long)f2bf(v.z) << 32)
          | ((unsigned long long)f2bf(v.w) << 48);
        __builtin_nontemporal_store(h, &xh64[i]);
    }

    // histogram with rank capture (atomicAdd return = within-row rank)
    for (int e = gid; e < E; e += gsz) {
        int r = __builtin_nontemporal_load(&rows[e]);
        int rk = atomicAdd(&counts[r], 1);
        __builtin_nontemporal_store(rk, &rank[e]);
    }
}

// ---------------- scans ----------------

__global__ __launch_bounds__(256) void scan1_kernel(
    int* __restrict__ start, int* __restrict__ bsums, int n) {
    __shared__ int tmp[256];
    int tid = threadIdx.x;
    int i = blockIdx.x * 256 + tid;
    int v = (i < n) ? start[i] : 0;
    tmp[tid] = v;
    __syncthreads();
    for (int off = 1; off < 256; off <<= 1) {
        int t = (tid >= off) ? tmp[tid - off] : 0;
        __syncthreads();
        tmp[tid] += t;
        __syncthreads();
    }
    if (i < n) start[i] = tmp[tid] - v;   // exclusive within tile
    if (tid == 255) bsums[blockIdx.x] = tmp[255];
}

__global__ __launch_bounds__(512) void scan2_kernel(int* __restrict__ bsums, int nb) {
    __shared__ int tmp[512];
    int tid = threadIdx.x;
    int v = (tid < nb) ? bsums[tid] : 0;
    tmp[tid] = v;
    __syncthreads();
    for (int off = 1; off < 512; off <<= 1) {
        int t = (tid >= off) ? tmp[tid - off] : 0;
        __syncthreads();
        tmp[tid] += t;
        __syncthreads();
    }
    if (tid < nb) bsums[tid] = tmp[tid] - v;
}

// ---------------- scatter (no atomics; scan3 math fused) ----------------

__global__ __launch_bounds__(256) void scatter_kernel(
    const int* __restrict__ rows, const int* __restrict__ cols,
    const float* __restrict__ w, const int* __restrict__ start,
    const int* __restrict__ bsums, const int* __restrict__ rank,
    long long* __restrict__ packed, int E) {
    int i = blockIdx.x * 256 + threadIdx.x;
    if (i >= E) return;
    int r = rows[i];
    int slot = start[r] + bsums[r >> 8] + rank[i];
    long long cw = (long long)(unsigned)cols[i]
                 | ((long long)__float_as_int(w[i]) << 32);
    __builtin_nontemporal_store(cw, &packed[slot]);
}

// ---------------- gather: one wave per row, bf16 x, fp32 accumulate --------

__global__ __launch_bounds__(256) void spmm_csr_bf16_kernel(
    const unsigned int* __restrict__ xh32,   // [N][64] uints (2 bf16 each)
    const int* __restrict__ start, const int* __restrict__ bsums,
    const long long* __restrict__ packed, float* __restrict__ out, int N, int E) {
    int wid = (int)((blockIdx.x * 256 + threadIdx.x) >> 6);  // row id
    int lane = threadIdx.x & 63;
    if (wid >= N) return;

    int s = start[wid] + bsums[wid >> 8];
    int t = (wid + 1 < N) ? (start[wid + 1] + bsums[(wid + 1) >> 8]) : E;

    float accx = 0.f, accy = 0.f;

    int e = s;
    for (; e + 3 < t; e += 4) {
        long long cw0 = __builtin_nontemporal_load(packed + e);
        long long cw1 = __builtin_nontemporal_load(packed + e + 1);
        long long cw2 = __builtin_nontemporal_load(packed + e + 2);
        long long cw3 = __builtin_nontemporal_load(packed + e + 3);
        unsigned v0 = xh32[(size_t)(int)(cw0 & 0xffffffff) * 64 + lane];
        unsigned v1 = xh32[(size_t)(int)(cw1 & 0xffffffff) * 64 + lane];
        unsigned v2 = xh32[(size_t)(int)(cw2 & 0xffffffff) * 64 + lane];
        unsigned v3 = xh32[(size_t)(int)(cw3 & 0xffffffff) * 64 + lane];
        float w0 = __int_as_float((int)(cw0 >> 32));
        float w1 = __int_as_float((int)(cw1 >> 32));
        float w2 = __int_as_float((int)(cw2 >> 32));
        float w3 = __int_as_float((int)(cw3 >> 32));
        accx += w0 * __uint_as_float(v0 << 16);
        accy += w0 * __uint_as_float(v0 & 0xffff0000u);
        accx += w1 * __uint_as_float(v1 << 16);
        accy += w1 * __uint_as_float(v1 & 0xffff0000u);
        accx += w2 * __uint_as_float(v2 << 16);
        accy += w2 * __uint_as_float(v2 & 0xffff0000u);
        accx += w3 * __uint_as_float(v3 << 16);
        accy += w3 * __uint_as_float(v3 & 0xffff0000u);
    }
    for (; e < t; ++e) {
        long long cw = __builtin_nontemporal_load(packed + e);
        unsigned v = xh32[(size_t)(int)(cw & 0xffffffff) * 64 + lane];
        float w0 = __int_as_float((int)(cw >> 32));
        accx += w0 * __uint_as_float(v << 16);
        accy += w0 * __uint_as_float(v & 0xffff0000u);
    }
    f32x2 a; a.x = accx; a.y = accy;
    __builtin_nontemporal_store(a, reinterpret_cast<f32x2*>(out) + (size_t)wid * 64 + lane);
}

// ---------------- fp32 CSR path (fallback if ws too small for xh) ----------

__global__ __launch_bounds__(256) void spmm_csr_kernel(
    const float* __restrict__ x, const int* __restrict__ start,
    const int* __restrict__ bsums, const long long* __restrict__ packed,
    float* __restrict__ out, int N, int E) {
    int wid = (int)((blockIdx.x * 256 + threadIdx.x) >> 6);
    int lane = threadIdx.x & 63;
    if (wid >= N) return;
    int s = start[wid] + bsums[wid >> 8];
    int t = (wid + 1 < N) ? (start[wid + 1] + bsums[(wid + 1) >> 8]) : E;
    const float2* x2 = reinterpret_cast<const float2*>(x);
    float accx = 0.f, accy = 0.f;
    for (int e = s; e < t; ++e) {
        long long cw = __builtin_nontemporal_load(packed + e);
        float2 v = x2[(size_t)(int)(cw & 0xffffffff) * 64 + lane];
        float w0 = __int_as_float((int)(cw >> 32));
        accx += w0 * v.x; accy += w0 * v.y;
    }
    f32x2 a; a.x = accx; a.y = accy;
    __builtin_nontemporal_store(a, reinterpret_cast<f32x2*>(out) + (size_t)wid * 64 + lane);
}

__global__ __launch_bounds__(256) void hist_rank_kernel(
    const int* __restrict__ rows, int* __restrict__ counts,
    int* __restrict__ rank, int E) {
    int i = blockIdx.x * 256 + threadIdx.x;
    if (i < E) rank[i] = atomicAdd(&counts[rows[i]], 1);
}

// ---------------- last-resort fallback (atomic scatter) ----------------

__global__ __launch_bounds__(256) void spmm_scatter_kernel(
    const float* __restrict__ x, const int* __restrict__ edge_index,
    const float* __restrict__ edge_values, float* __restrict__ out, int E) {
    long long t = (long long)blockIdx.x * blockDim.x + threadIdx.x;
    int e = (int)(t >> 5);
    int part = (int)(t & 31);
    if (e >= E) return;
    int row = edge_index[e];
    int col = edge_index[E + e];
    float w = edge_values[e];
    const float4* xrow = reinterpret_cast<const float4*>(x + (size_t)col * D_FEAT);
    float4 v = xrow[part];
    float* o = out + (size_t)row * D_FEAT + part * 4;
    unsafeAtomicAdd(o + 0, v.x * w);
    unsafeAtomicAdd(o + 1, v.y * w);
    unsafeAtomicAdd(o + 2, v.z * w);
    unsafeAtomicAdd(o + 3, v.w * w);
}

// ---------------- launch ----------------

extern "C" void kernel_launch(void* const* d_in, const int* in_sizes, int n_in,
                              void* d_out, int out_size, void* d_ws, size_t ws_size,
                              hipStream_t stream) {
    const float* x           = (const float*)d_in[0];
    const int*   edge_index  = (const int*)d_in[1];
    const float* edge_values = (const float*)d_in[2];
    float*       out         = (float*)d_out;

    int E = in_sizes[2];
    int N = out_size / D_FEAT;
    const int* rows = edge_index;
    const int* cols = edge_index + E;
    int nb = (N + 255) / 256;
    int ebl = (E + 255) / 256;
    int gbl = (int)(((long long)N * 64 + 255) / 256);

    // ws layout: start(N+1) | bsums(512) | rank(E) | packed(E i64) | xh(N*D bf16)
    size_t off = 0;
    int* start = (int*)((char*)d_ws + off); off += (size_t)(N + 1) * sizeof(int);
    int* bsums = (int*)((char*)d_ws + off); off += 512 * sizeof(int);
    int* rank  = (int*)((char*)d_ws + off); off += (size_t)E * sizeof(int);
    off = (off + 15) & ~(size_t)15;
    long long* packed = (long long*)((char*)d_ws + off); off += (size_t)E * sizeof(long long);
    size_t off_csr_only = off;
    off = (off + 15) & ~(size_t)15;
    unsigned short* xh = (unsigned short*)((char*)d_ws + off);
    off += (size_t)N * D_FEAT * sizeof(unsigned short);

    if (off <= ws_size && nb <= 512) {
        // bf16-gather path
        hipMemsetAsync(start, 0, (size_t)(N + 1) * sizeof(int), stream);
        int nfeat4 = N * D_FEAT / 4;
        convert_hist_kernel<<<ebl, 256, 0, stream>>>(
            x, (unsigned long long*)xh, nfeat4, rows, start, rank, E);
        scan1_kernel<<<nb, 256, 0, stream>>>(start, bsums, N);
        scan2_kernel<<<1, 512, 0, stream>>>(bsums, nb);
        scatter_kernel<<<ebl, 256, 0, stream>>>(rows, cols, edge_values, start,
                                                bsums, rank, packed, E);
        spmm_csr_bf16_kernel<<<gbl, 256, 0, stream>>>(
            (const unsigned int*)xh, start, bsums, packed, out, N, E);
        return;
    }

    if (off_csr_only <= ws_size && nb <= 512) {
        // fp32 CSR path
        hipMemsetAsync(start, 0, (size_t)(N + 1) * sizeof(int), stream);
        hist_rank_kernel<<<ebl, 256, 0, stream>>>(rows, start, rank, E);
        scan1_kernel<<<nb, 256, 0, stream>>>(start, bsums, N);
        scan2_kernel<<<1, 512, 0, stream>>>(bsums, nb);
        scatter_kernel<<<ebl, 256, 0, stream>>>(rows, cols, edge_values, start,
                                                bsums, rank, packed, E);
        spmm_csr_kernel<<<gbl, 256, 0, stream>>>(x, start, bsums, packed, out, N, E);
        return;
    }

    // last-resort: atomic scatter
    hipMemsetAsync(d_out, 0, (size_t)out_size * sizeof(float), stream);
    long long total_threads = (long long)E * 32;
    long long grid = (total_threads + 255) / 256;
    spmm_scatter_kernel<<<(dim3)(unsigned)grid, 256, 0, stream>>>(
        x, edge_index, edge_values, out, E);
}

// Round 7
// 198.853 us; speedup vs baseline: 1.1983x; 1.1983x over previous
//
#include <hip/hip_runtime.h>
#include <hip/hip_bf16.h>

// COO SpMM: out[row[e], :] += ev[e] * x[col[e], :]
// N=100000, E=1600000, D=128 fp32.
//
// Round 7: (a) un-fuse convert from hist (fused version cost +37us vs +12us
// stream); convert kernel also zeroes counts (kills memset dispatch).
// (b) scatter back to plain stores (NT on random 8B writes defeats L2 write
// coalescing). (c) gather software-pipelined: prefetch next 4 packed entries
// while current 4 gathers are in flight (clamp idx + zero weight tail).

#define D_FEAT 128

typedef float f32x2 __attribute__((ext_vector_type(2)));

static __device__ __forceinline__ unsigned short f2bf(float f) {
    unsigned u = __float_as_uint(f);
    u += 0x7fffu + ((u >> 16) & 1u);   // round-to-nearest-even
    return (unsigned short)(u >> 16);
}
static __device__ __forceinline__ float bf_lo(unsigned v) {
    return __uint_as_float(v << 16);
}
static __device__ __forceinline__ float bf_hi(unsigned v) {
    return __uint_as_float(v & 0xffff0000u);
}

// ---------------- convert x->bf16 + zero counts (pure stream) ----------------

__global__ __launch_bounds__(256) void convert_zero_kernel(
    const float* __restrict__ x, unsigned long long* __restrict__ xh64, int nfeat4,
    int* __restrict__ counts, int ncounts) {
    int gid = blockIdx.x * 256 + threadIdx.x;
    int gsz = gridDim.x * 256;
    for (int i = gid; i < ncounts; i += gsz) counts[i] = 0;
    const float4* x4 = reinterpret_cast<const float4*>(x);
    for (int i = gid; i < nfeat4; i += gsz) {
        float4 v = x4[i];
        unsigned long long h =
            (unsigned long long)f2bf(v.x)
          | ((unsigned long long)f2bf(v.y) << 16)
          | ((unsigned long long)f2bf(v.z) << 32)
          | ((unsigned long long)f2bf(v.w) << 48);
        __builtin_nontemporal_store(h, &xh64[i]);
    }
}

// ---------------- histogram with rank capture ----------------

__global__ __launch_bounds__(256) void hist_rank_kernel(
    const int* __restrict__ rows, int* __restrict__ counts,
    int* __restrict__ rank, int E) {
    int i = blockIdx.x * 256 + threadIdx.x;
    if (i < E) rank[i] = atomicAdd(&counts[rows[i]], 1);
}

// ---------------- scans ----------------

__global__ __launch_bounds__(256) void scan1_kernel(
    int* __restrict__ start, int* __restrict__ bsums, int n) {
    __shared__ int tmp[256];
    int tid = threadIdx.x;
    int i = blockIdx.x * 256 + tid;
    int v = (i < n) ? start[i] : 0;
    tmp[tid] = v;
    __syncthreads();
    for (int off = 1; off < 256; off <<= 1) {
        int t = (tid >= off) ? tmp[tid - off] : 0;
        __syncthreads();
        tmp[tid] += t;
        __syncthreads();
    }
    if (i < n) start[i] = tmp[tid] - v;   // exclusive within tile
    if (tid == 255) bsums[blockIdx.x] = tmp[255];
}

__global__ __launch_bounds__(512) void scan2_kernel(int* __restrict__ bsums, int nb) {
    __shared__ int tmp[512];
    int tid = threadIdx.x;
    int v = (tid < nb) ? bsums[tid] : 0;
    tmp[tid] = v;
    __syncthreads();
    for (int off = 1; off < 512; off <<= 1) {
        int t = (tid >= off) ? tmp[tid - off] : 0;
        __syncthreads();
        tmp[tid] += t;
        __syncthreads();
    }
    if (tid < nb) bsums[tid] = tmp[tid] - v;
}

// ---------------- scatter (no atomics, plain L2-allocating stores) ----------

__global__ __launch_bounds__(256) void scatter_kernel(
    const int* __restrict__ rows, const int* __restrict__ cols,
    const float* __restrict__ w, const int* __restrict__ start,
    const int* __restrict__ bsums, const int* __restrict__ rank,
    long long* __restrict__ packed, int E) {
    int i = blockIdx.x * 256 + threadIdx.x;
    if (i >= E) return;
    int r = rows[i];
    int slot = start[r] + bsums[r >> 8] + rank[i];
    long long cw = (long long)(unsigned)cols[i]
                 | ((long long)__float_as_int(w[i]) << 32);
    packed[slot] = cw;
}

// ------- gather: one wave per row, bf16 x, software-pipelined packed -------

__global__ __launch_bounds__(256) void spmm_csr_bf16_kernel(
    const unsigned int* __restrict__ xh32,   // [N][64] uints (2 bf16 each)
    const int* __restrict__ start, const int* __restrict__ bsums,
    const long long* __restrict__ packed, float* __restrict__ out, int N, int E) {
    int wid = (int)((blockIdx.x * 256 + threadIdx.x) >> 6);  // row id
    int lane = threadIdx.x & 63;
    if (wid >= N) return;

    int s = start[wid] + bsums[wid >> 8];
    int t = (wid + 1 < N) ? (start[wid + 1] + bsums[(wid + 1) >> 8]) : E;

    f32x2 zero; zero.x = 0.f; zero.y = 0.f;
    f32x2* optr = reinterpret_cast<f32x2*>(out) + (size_t)wid * 64 + lane;
    if (s >= t) {  // empty row
        __builtin_nontemporal_store(zero, optr);
        return;
    }

    int tm1 = t - 1;
    float accx = 0.f, accy = 0.f;

    // prologue: first 4 packed entries (clamped)
    long long p0 = packed[min(s + 0, tm1)];
    long long p1 = packed[min(s + 1, tm1)];
    long long p2 = packed[min(s + 2, tm1)];
    long long p3 = packed[min(s + 3, tm1)];

    for (int e = s; e < t; e += 4) {
        int en = e + 4;
        // prefetch next 4 (independent of this iteration's gathers)
        long long q0 = packed[min(en + 0, tm1)];
        long long q1 = packed[min(en + 1, tm1)];
        long long q2 = packed[min(en + 2, tm1)];
        long long q3 = packed[min(en + 3, tm1)];
        // gathers for current 4
        unsigned v0 = xh32[(size_t)(unsigned)(p0 & 0xffffffff) * 64 + lane];
        unsigned v1 = xh32[(size_t)(unsigned)(p1 & 0xffffffff) * 64 + lane];
        unsigned v2 = xh32[(size_t)(unsigned)(p2 & 0xffffffff) * 64 + lane];
        unsigned v3 = xh32[(size_t)(unsigned)(p3 & 0xffffffff) * 64 + lane];
        // zero weights past end (loads above are clamped-valid duplicates)
        float w0 = (e + 0 < t) ? __int_as_float((int)(p0 >> 32)) : 0.f;
        float w1 = (e + 1 < t) ? __int_as_float((int)(p1 >> 32)) : 0.f;
        float w2 = (e + 2 < t) ? __int_as_float((int)(p2 >> 32)) : 0.f;
        float w3 = (e + 3 < t) ? __int_as_float((int)(p3 >> 32)) : 0.f;
        accx += w0 * bf_lo(v0); accy += w0 * bf_hi(v0);
        accx += w1 * bf_lo(v1); accy += w1 * bf_hi(v1);
        accx += w2 * bf_lo(v2); accy += w2 * bf_hi(v2);
        accx += w3 * bf_lo(v3); accy += w3 * bf_hi(v3);
        p0 = q0; p1 = q1; p2 = q2; p3 = q3;
    }
    f32x2 a; a.x = accx; a.y = accy;
    __builtin_nontemporal_store(a, optr);
}

// ---------------- fp32 CSR path (fallback if ws too small for xh) ----------

__global__ __launch_bounds__(256) void spmm_csr_kernel(
    const float* __restrict__ x, const int* __restrict__ start,
    const int* __restrict__ bsums, const long long* __restrict__ packed,
    float* __restrict__ out, int N, int E) {
    int wid = (int)((blockIdx.x * 256 + threadIdx.x) >> 6);
    int lane = threadIdx.x & 63;
    if (wid >= N) return;
    int s = start[wid] + bsums[wid >> 8];
    int t = (wid + 1 < N) ? (start[wid + 1] + bsums[(wid + 1) >> 8]) : E;
    const float2* x2 = reinterpret_cast<const float2*>(x);
    float accx = 0.f, accy = 0.f;
    for (int e = s; e < t; ++e) {
        long long cw = packed[e];
        float2 v = x2[(size_t)(int)(cw & 0xffffffff) * 64 + lane];
        float w0 = __int_as_float((int)(cw >> 32));
        accx += w0 * v.x; accy += w0 * v.y;
    }
    f32x2 a; a.x = accx; a.y = accy;
    __builtin_nontemporal_store(a, reinterpret_cast<f32x2*>(out) + (size_t)wid * 64 + lane);
}

// ---------------- last-resort fallback (atomic scatter) ----------------

__global__ __launch_bounds__(256) void spmm_scatter_kernel(
    const float* __restrict__ x, const int* __restrict__ edge_index,
    const float* __restrict__ edge_values, float* __restrict__ out, int E) {
    long long t = (long long)blockIdx.x * blockDim.x + threadIdx.x;
    int e = (int)(t >> 5);
    int part = (int)(t & 31);
    if (e >= E) return;
    int row = edge_index[e];
    int col = edge_index[E + e];
    float w = edge_values[e];
    const float4* xrow = reinterpret_cast<const float4*>(x + (size_t)col * D_FEAT);
    float4 v = xrow[part];
    float* o = out + (size_t)row * D_FEAT + part * 4;
    unsafeAtomicAdd(o + 0, v.x * w);
    unsafeAtomicAdd(o + 1, v.y * w);
    unsafeAtomicAdd(o + 2, v.z * w);
    unsafeAtomicAdd(o + 3, v.w * w);
}

// ---------------- launch ----------------

extern "C" void kernel_launch(void* const* d_in, const int* in_sizes, int n_in,
                              void* d_out, int out_size, void* d_ws, size_t ws_size,
                              hipStream_t stream) {
    const float* x           = (const float*)d_in[0];
    const int*   edge_index  = (const int*)d_in[1];
    const float* edge_values = (const float*)d_in[2];
    float*       out         = (float*)d_out;

    int E = in_sizes[2];
    int N = out_size / D_FEAT;
    const int* rows = edge_index;
    const int* cols = edge_index + E;
    int nb = (N + 255) / 256;
    int ebl = (E + 255) / 256;
    int gbl = (int)(((long long)N * 64 + 255) / 256);

    // ws layout: start(N+1) | bsums(512) | rank(E) | packed(E i64) | xh(N*D bf16)
    size_t off = 0;
    int* start = (int*)((char*)d_ws + off); off += (size_t)(N + 1) * sizeof(int);
    int* bsums = (int*)((char*)d_ws + off); off += 512 * sizeof(int);
    int* rank  = (int*)((char*)d_ws + off); off += (size_t)E * sizeof(int);
    off = (off + 15) & ~(size_t)15;
    long long* packed = (long long*)((char*)d_ws + off); off += (size_t)E * sizeof(long long);
    size_t off_csr_only = off;
    off = (off + 15) & ~(size_t)15;
    unsigned short* xh = (unsigned short*)((char*)d_ws + off);
    off += (size_t)N * D_FEAT * sizeof(unsigned short);

    if (off <= ws_size && nb <= 512) {
        // bf16-gather path
        int nfeat4 = N * D_FEAT / 4;
        convert_zero_kernel<<<2048, 256, 0, stream>>>(
            x, (unsigned long long*)xh, nfeat4, start, N + 1);
        hist_rank_kernel<<<ebl, 256, 0, stream>>>(rows, start, rank, E);
        scan1_kernel<<<nb, 256, 0, stream>>>(start, bsums, N);
        scan2_kernel<<<1, 512, 0, stream>>>(bsums, nb);
        scatter_kernel<<<ebl, 256, 0, stream>>>(rows, cols, edge_values, start,
                                                bsums, rank, packed, E);
        spmm_csr_bf16_kernel<<<gbl, 256, 0, stream>>>(
            (const unsigned int*)xh, start, bsums, packed, out, N, E);
        return;
    }

    if (off_csr_only <= ws_size && nb <= 512) {
        // fp32 CSR path
        hipMemsetAsync(start, 0, (size_t)(N + 1) * sizeof(int), stream);
        hist_rank_kernel<<<ebl, 256, 0, stream>>>(rows, start, rank, E);
        scan1_kernel<<<nb, 256, 0, stream>>>(start, bsums, N);
        scan2_kernel<<<1, 512, 0, stream>>>(bsums, nb);
        scatter_kernel<<<ebl, 256, 0, stream>>>(rows, cols, edge_values, start,
                                                bsums, rank, packed, E);
        spmm_csr_kernel<<<gbl, 256, 0, stream>>>(x, start, bsums, packed, out, N, E);
        return;
    }

    // last-resort: atomic scatter
    hipMemsetAsync(d_out, 0, (size_t)out_size * sizeof(float), stream);
    long long total_threads = (long long)E * 32;
    long long grid = (total_threads + 255) / 256;
    spmm_scatter_kernel<<<(dim3)(unsigned)grid, 256, 0, stream>>>(
        x, edge_index, edge_values, out, E);
}